// Round 1
// baseline (1219.885 us; speedup 1.0000x reference)
//
#include <hip/hip_runtime.h>
#include <hip/hip_bf16.h>
#include <math.h>

// Problem constants (fixed by reference file)
#define NN   100000   // nodes
#define NE   640000   // edges
#define DIN  128      // in_channels
#define DO   128      // out_channels (H*C)
#define ED   256      // edge dim (MSG + TD)
#define MSGD 128
#define NBLK 391      // ceil(NN/256) for scan kernels

typedef __attribute__((ext_vector_type(8))) short s16x8;           // 8 bf16 (A/B frag)
typedef __attribute__((ext_vector_type(4))) float f32x4;           // C/D frag
typedef __attribute__((ext_vector_type(4))) unsigned short u16x4;
typedef __attribute__((ext_vector_type(8))) unsigned short u16x8;

__device__ __forceinline__ unsigned short f2bs(float f) {
    __hip_bfloat16 h = __float2bfloat16(f);   // RNE
    return __builtin_bit_cast(unsigned short, h);
}
__device__ __forceinline__ float bs2f(unsigned short u) {
    return __uint_as_float(((unsigned int)u) << 16);
}
__device__ __forceinline__ float fast_cos(float x) {
    float rev = x * 0.15915494309189535f;   // 1/(2pi)
    rev = rev - rintf(rev);                 // revolutions, range-reduced
    return __builtin_amdgcn_cosf(rev);
}

// ---------------------------------------------------------------------------
// Kernel 0: weight transposes to bf16 (tiny).
// WT[n][k] = bf16(W[k][n]) for We, Wq, Wk, Wv, Wskip.
// ---------------------------------------------------------------------------
__global__ __launch_bounds__(256) void convert_kernel(
    const float* __restrict__ We,
    const float* __restrict__ Wq, const float* __restrict__ Wk,
    const float* __restrict__ Wv, const float* __restrict__ Ws,
    unsigned short* __restrict__ WeT,
    unsigned short* __restrict__ WqT, unsigned short* __restrict__ WkT,
    unsigned short* __restrict__ WvT, unsigned short* __restrict__ WsT)
{
    const int T0  = ED * DO;            // 32768 (WeT)
    const int TOT = T0 + 4 * DIN * DO;  // + 4 node mats
    int i = blockIdx.x * 256 + threadIdx.x;
    if (i >= TOT) return;
    if (i < T0) {
        int n = i >> 8, k = i & 255;
        WeT[i] = f2bs(We[(size_t)k * DO + n]);
    } else {
        int j = i - T0; int m = j >> 14; int r = j & 16383;
        int n = r >> 7, k = r & 127;
        const float* W = (m == 0) ? Wq : (m == 1) ? Wk : (m == 2) ? Wv : Ws;
        unsigned short* WD = (m == 0) ? WqT : (m == 1) ? WkT : (m == 2) ? WvT : WsT;
        WD[r] = f2bs(W[(size_t)k * DO + n]);
    }
}

// ---------------------------------------------------------------------------
// Kernel 1: node projections via MFMA. 64 nodes/block, 256 threads (4 waves).
// x (fp32) is converted to bf16 during LDS staging (no xb buffer).
// Q,K,V stored bf16 (halves edge-gather traffic); SKIP stored fp32.
// ---------------------------------------------------------------------------
__global__ __launch_bounds__(256) void node_proj_kernel(
    const float* __restrict__ x,
    const unsigned short* __restrict__ WqT, const float* __restrict__ bq,
    const unsigned short* __restrict__ WkT, const float* __restrict__ bk,
    const unsigned short* __restrict__ WvT, const float* __restrict__ bv,
    const unsigned short* __restrict__ WsT, const float* __restrict__ bs,
    unsigned short* __restrict__ Qb, unsigned short* __restrict__ Kb,
    unsigned short* __restrict__ Vb, float* __restrict__ SKIP)
{
    __shared__ unsigned short xt[64 * 136];   // 64 nodes x 128k, pad +8
    const int tid = threadIdx.x;
    const int n0  = blockIdx.x * 64;

    #pragma unroll
    for (int i = 0; i < 8; ++i) {             // 64 rows x 32 float4 / 256 thr
        int q = i * 256 + tid; int row = q >> 5, c4 = q & 31;
        int gn = n0 + row; if (gn > NN - 1) gn = NN - 1;
        float4 v = ((const float4*)(x + (size_t)gn * DIN))[c4];
        u16x4 b; b.x = f2bs(v.x); b.y = f2bs(v.y); b.z = f2bs(v.z); b.w = f2bs(v.w);
        *(u16x4*)(xt + row * 136 + c4 * 4) = b;
    }
    __syncthreads();

    const int lane = tid & 63, w = tid >> 6;
    const int l15 = lane & 15, quad = lane >> 4;
    const unsigned short* arow = xt + (w * 16 + l15) * 136 + quad * 8;

    const unsigned short* WT[4] = {WqT, WkT, WvT, WsT};
    const float*          BI[4] = {bq, bk, bv, bs};

    #pragma unroll
    for (int m = 0; m < 4; ++m) {
        f32x4 acc[8];
        #pragma unroll
        for (int j = 0; j < 8; ++j) { float b = BI[m][j * 16 + l15]; acc[j] = {b, b, b, b}; }
        const unsigned short* Wm = WT[m];
        #pragma unroll
        for (int ks = 0; ks < 4; ++ks) {
            s16x8 a = *(const s16x8*)(arow + ks * 32);
            #pragma unroll
            for (int j = 0; j < 8; ++j) {
                s16x8 bf = *(const s16x8*)(Wm + (j * 16 + l15) * DIN + ks * 32 + quad * 8);
                acc[j] = __builtin_amdgcn_mfma_f32_16x16x32_bf16(a, bf, acc[j], 0, 0, 0);
            }
        }
        #pragma unroll
        for (int j = 0; j < 8; ++j) {
            int col = j * 16 + l15;
            #pragma unroll
            for (int r = 0; r < 4; ++r) {
                int node = n0 + w * 16 + quad * 4 + r;
                if (node < NN) {
                    float v = acc[j][r];
                    if (m == 0)      Qb[(size_t)node * DO + col] = f2bs(v);
                    else if (m == 1) Kb[(size_t)node * DO + col] = f2bs(v);
                    else if (m == 2) Vb[(size_t)node * DO + col] = f2bs(v);
                    else             SKIP[(size_t)node * DO + col] = v;
                }
            }
        }
    }
}

// ---------------------------------------------------------------------------
// Counting sort of edges by dst -> CSR (rowptr, perm). All tiny kernels.
// ---------------------------------------------------------------------------
__global__ __launch_bounds__(256) void hist_kernel(
    const int* __restrict__ dstI, int* __restrict__ counts)
{
    int e = blockIdx.x * 256 + threadIdx.x;
    if (e < NE) atomicAdd(&counts[dstI[e]], 1);
}

__global__ __launch_bounds__(256) void scan1_kernel(
    const int* __restrict__ counts, int* __restrict__ bsum)
{
    __shared__ int s[256];
    int t = threadIdx.x; int i = blockIdx.x * 256 + t;
    s[t] = (i < NN) ? counts[i] : 0;
    __syncthreads();
    #pragma unroll
    for (int off = 128; off; off >>= 1) {
        if (t < off) s[t] += s[t + off];
        __syncthreads();
    }
    if (t == 0) bsum[blockIdx.x] = s[0];
}

__global__ __launch_bounds__(512) void scan2_kernel(int* __restrict__ bsum)
{
    __shared__ int s[512];
    int t = threadIdx.x;
    int v = (t < NBLK) ? bsum[t] : 0;
    s[t] = v; __syncthreads();
    for (int off = 1; off < 512; off <<= 1) {
        int add = (t >= off) ? s[t - off] : 0;
        __syncthreads();
        s[t] += add;
        __syncthreads();
    }
    if (t < NBLK) bsum[t] = s[t] - v;   // exclusive
}

__global__ __launch_bounds__(256) void scan3_kernel(
    const int* __restrict__ counts, const int* __restrict__ bsum,
    int* __restrict__ rowptr)
{
    __shared__ int s[256];
    int t = threadIdx.x; int i = blockIdx.x * 256 + t;
    int v = (i < NN) ? counts[i] : 0;
    s[t] = v; __syncthreads();
    for (int off = 1; off < 256; off <<= 1) {
        int add = (t >= off) ? s[t - off] : 0;
        __syncthreads();
        s[t] += add;
        __syncthreads();
    }
    if (i < NN) rowptr[i] = bsum[blockIdx.x] + s[t] - v;
    if (i == 0) rowptr[NN] = NE;
}

__global__ __launch_bounds__(256) void scatter_kernel(
    const int* __restrict__ dstI, const int* __restrict__ rowptr,
    int* __restrict__ cursor, int* __restrict__ perm)
{
    int e = blockIdx.x * 256 + threadIdx.x;
    if (e < NE) {
        int d = dstI[e];
        int pos = rowptr[d] + atomicAdd(&cursor[d], 1);
        perm[pos] = e;
    }
}

// ---------------------------------------------------------------------------
// Kernel 2 (phase A): edge kernel. 64 edges/block, 256 threads (4 waves).
// attr (bf16) staged in LDS -> e = attr @ We via MFMA -> e tiles written back
// into the SAME LDS buffer (fp32) -> per-edge alpha / exp.
// NO ATOMICS: stores ea (fp32 per edge-head) and VE = bf16(v + e) per col.
// No segment-max: |alpha| <~ 12, exp safe in fp32, result identical.
// ---------------------------------------------------------------------------
__global__ __launch_bounds__(256) void edge_kernel(
    const float* __restrict__ last_update, const float* __restrict__ tarr,
    const float* __restrict__ msg,
    const float* __restrict__ w_time, const float* __restrict__ b_time,
    const unsigned short* __restrict__ WeT,
    const int* __restrict__ srcI, const int* __restrict__ dstI,
    const unsigned short* __restrict__ Qb, const unsigned short* __restrict__ Kb,
    const unsigned short* __restrict__ Vb,
    unsigned short* __restrict__ VE, float* __restrict__ EA)
{
    // 64 rows x 528B: as bf16 attr rows (264 elems, 256 + 8 pad),
    // then reused as fp32 e rows (132 elems, 128 + 4 pad).
    __shared__ char smem[64 * 528];
    __shared__ int   ssrc[64], sdst[64];
    __shared__ float srel[64];
    const int tid = threadIdx.x;
    const int e0  = blockIdx.x * 64;

    if (tid < 64) {
        int s = srcI[e0 + tid], d = dstI[e0 + tid];
        ssrc[tid] = s; sdst[tid] = d;
        srel[tid] = last_update[s] - tarr[e0 + tid];
    }
    __syncthreads();

    unsigned short* at = (unsigned short*)smem;
    // stage msg -> bf16 (coalesced float4 reads)
    const float4* msg4 = (const float4*)msg;
    #pragma unroll
    for (int i = 0; i < 8; ++i) {
        int q = i * 256 + tid; int e = q >> 5, c4 = q & 31;
        float4 m4 = msg4[(size_t)(e0 + e) * 32 + c4];
        u16x4 b; b.x = f2bs(m4.x); b.y = f2bs(m4.y); b.z = f2bs(m4.z); b.w = f2bs(m4.w);
        *(u16x4*)(at + e * 264 + c4 * 4) = b;
    }
    // stage time encoding -> bf16
    #pragma unroll
    for (int i = 0; i < 32; ++i) {
        int q = i * 256 + tid; int e = q >> 7, j = q & 127;
        float v = fast_cos(srel[e] * w_time[j] + b_time[j]);
        at[e * 264 + MSGD + j] = f2bs(v);
    }
    __syncthreads();

    const int lane = tid & 63, w = tid >> 6;
    const int l15 = lane & 15, quad = lane >> 4;

    // MFMA: wave w computes edges w*16..w*16+15 x all 128 cols
    f32x4 acc[8];
    #pragma unroll
    for (int j = 0; j < 8; ++j) acc[j] = {0.f, 0.f, 0.f, 0.f};
    const unsigned short* arow = at + (w * 16 + l15) * 264 + quad * 8;
    #pragma unroll
    for (int ks = 0; ks < 8; ++ks) {
        s16x8 a = *(const s16x8*)(arow + ks * 32);
        #pragma unroll
        for (int j = 0; j < 8; ++j) {
            s16x8 b = *(const s16x8*)(WeT + (j * 16 + l15) * ED + ks * 32 + quad * 8);
            acc[j] = __builtin_amdgcn_mfma_f32_16x16x32_bf16(a, b, acc[j], 0, 0, 0);
        }
    }
    __syncthreads();   // attr fully consumed; reuse buffer for e (fp32)

    float* eld = (float*)smem;
    #pragma unroll
    for (int j = 0; j < 8; ++j) {
        #pragma unroll
        for (int r = 0; r < 4; ++r)
            eld[(w * 16 + quad * 4 + r) * 132 + j * 16 + l15] = acc[j][r];
    }
    __syncthreads();

    // per-edge: alpha = q[dst]·(k[src]+e)/8, ea = exp -> stored; VE = bf16(v+e)
    const int c = tid & 127;          // wave0: head0 cols, wave1: head1 cols
    const int g = tid >> 7;           // edge half
    const int h = c >> 6;
    #pragma unroll 4
    for (int i = 0; i < 32; ++i) {
        int e = g * 32 + i;
        int s = ssrc[e], d = sdst[e];
        float ev = eld[e * 132 + c];
        float qv = bs2f(Qb[(size_t)d * DO + c]);
        float kv = bs2f(Kb[(size_t)s * DO + c]);
        float vv = bs2f(Vb[(size_t)s * DO + c]);
        float p = qv * (kv + ev);
        #pragma unroll
        for (int off = 32; off; off >>= 1) p += __shfl_xor(p, off, 64);
        float ea = __expf(p * 0.125f);                 // / sqrt(C=64)
        VE[(size_t)(e0 + e) * DO + c] = f2bs(vv + ev);
        if (lane == 0) EA[(size_t)(e0 + e) * 2 + h] = ea;
    }
}

// ---------------------------------------------------------------------------
// Kernel 3 (phase B): node-major aggregation, one wave per node, no atomics.
// out[n][c] = (sum_e ea*VE) / (sum_e ea + 1e-16) + SKIP[n][c]
// Lane l handles cols 2l, 2l+1 (head = l>>5).
// ---------------------------------------------------------------------------
__global__ __launch_bounds__(256) void agg_kernel(
    const int* __restrict__ rowptr, const int* __restrict__ perm,
    const float* __restrict__ EA, const unsigned short* __restrict__ VE,
    const float* __restrict__ SKIP, float* __restrict__ out)
{
    int wid  = (blockIdx.x * 256 + threadIdx.x) >> 6;   // node
    int lane = threadIdx.x & 63;
    if (wid >= NN) return;
    int beg = rowptr[wid], end = rowptr[wid + 1];
    float a0 = 0.f, a1 = 0.f, den = 0.f;
    for (int j = beg; j < end; ++j) {
        int e = perm[j];
        float2 ea = ((const float2*)EA)[e];                         // broadcast
        unsigned int pv = ((const unsigned int*)(VE + (size_t)e * DO))[lane];
        float v0 = bs2f((unsigned short)(pv & 0xffffu));
        float v1 = bs2f((unsigned short)(pv >> 16));
        float eah = (lane < 32) ? ea.x : ea.y;
        den += eah;
        a0 += eah * v0;
        a1 += eah * v1;
    }
    float inv = 1.0f / (den + 1e-16f);
    float2 sk = ((const float2*)SKIP)[(size_t)wid * 64 + lane];
    float2 o;
    o.x = a0 * inv + sk.x;
    o.y = a1 * inv + sk.y;
    ((float2*)out)[(size_t)wid * 64 + lane] = o;
}

extern "C" void kernel_launch(void* const* d_in, const int* in_sizes, int n_in,
                              void* d_out, int out_size, void* d_ws, size_t ws_size,
                              hipStream_t stream) {
    const float* x           = (const float*)d_in[0];
    const float* last_update = (const float*)d_in[1];
    const float* tarr        = (const float*)d_in[2];
    const float* msg         = (const float*)d_in[3];
    const float* w_time      = (const float*)d_in[4];
    const float* b_time      = (const float*)d_in[5];
    const float* Wq          = (const float*)d_in[6];
    const float* bq          = (const float*)d_in[7];
    const float* Wk          = (const float*)d_in[8];
    const float* bk          = (const float*)d_in[9];
    const float* Wv          = (const float*)d_in[10];
    const float* bv          = (const float*)d_in[11];
    const float* We          = (const float*)d_in[12];
    const float* Ws          = (const float*)d_in[13];
    const float* bs          = (const float*)d_in[14];
    const int*   ei          = (const int*)d_in[15];
    const int*   srcI = ei;
    const int*   dstI = ei + NE;

    float* out = (float*)d_out;
    char*  ws  = (char*)d_ws;
    // byte layout (all 16B-aligned)
    unsigned short* Qb   = (unsigned short*)(ws);                    // 25,600,000
    unsigned short* Kb   = (unsigned short*)(ws + 25600000);         // 25,600,000
    unsigned short* Vb   = (unsigned short*)(ws + 51200000);         // 25,600,000
    unsigned short* WeT  = (unsigned short*)(ws + 76800000);         // 65,536
    unsigned short* WqT  = (unsigned short*)(ws + 76865536);         // 32,768
    unsigned short* WkT  = (unsigned short*)(ws + 76898304);         // 32,768
    unsigned short* WvT  = (unsigned short*)(ws + 76931072);         // 32,768
    unsigned short* WsT  = (unsigned short*)(ws + 76963840);         // 32,768
    float*          SKIP = (float*)(ws + 76996608);                  // 51,200,000
    unsigned short* VE   = (unsigned short*)(ws + 128196608);        // 163,840,000
    float*          EA   = (float*)(ws + 292036608);                 // 5,120,000
    int*            perm = (int*)(ws + 297156608);                   // 2,560,000
    int*            counts = (int*)(ws + 299716608);                 // 400,000
    int*            cursor = (int*)(ws + 300116608);                 // 400,000
    int*            rowptr = (int*)(ws + 300516608);                 // 400,016
    int*            bsum   = (int*)(ws + 300916624);                 // 2,048

    // zero counts + cursor (contiguous, 800 KB)
    hipMemsetAsync(counts, 0, 800000, stream);

    convert_kernel<<<384, 256, 0, stream>>>(
        We, Wq, Wk, Wv, Ws, WeT, WqT, WkT, WvT, WsT);

    node_proj_kernel<<<(NN + 63) / 64, 256, 0, stream>>>(
        x, WqT, bq, WkT, bk, WvT, bv, WsT, bs, Qb, Kb, Vb, SKIP);

    // CSR build (counting sort by dst)
    hist_kernel<<<(NE + 255) / 256, 256, 0, stream>>>(dstI, counts);
    scan1_kernel<<<NBLK, 256, 0, stream>>>(counts, bsum);
    scan2_kernel<<<1, 512, 0, stream>>>(bsum);
    scan3_kernel<<<NBLK, 256, 0, stream>>>(counts, bsum, rowptr);
    scatter_kernel<<<(NE + 255) / 256, 256, 0, stream>>>(dstI, rowptr, cursor, perm);

    edge_kernel<<<NE / 64, 256, 0, stream>>>(
        last_update, tarr, msg, w_time, b_time, WeT, srcI, dstI,
        Qb, Kb, Vb, VE, EA);

    agg_kernel<<<(NN * 64 + 255) / 256, 256, 0, stream>>>(
        rowptr, perm, EA, VE, SKIP, out);
}

// Round 2
// 1005.074 us; speedup vs baseline: 1.2137x; 1.2137x over previous
//
#include <hip/hip_runtime.h>
#include <hip/hip_bf16.h>
#include <math.h>

// Problem constants (fixed by reference file)
#define NN   100000   // nodes
#define NE   640000   // edges
#define DIN  128      // in_channels
#define DO   128      // out_channels (H*C)
#define ED   256      // edge dim (MSG + TD)
#define MSGD 128
#define NBLK 391      // ceil(NN/256) for scan kernels

typedef __attribute__((ext_vector_type(8))) short s16x8;           // 8 bf16 (A/B frag)
typedef __attribute__((ext_vector_type(4))) float f32x4;           // C/D frag
typedef __attribute__((ext_vector_type(4))) unsigned short u16x4;
typedef __attribute__((ext_vector_type(8))) unsigned short u16x8;

__device__ __forceinline__ unsigned short f2bs(float f) {
    __hip_bfloat16 h = __float2bfloat16(f);   // RNE
    return __builtin_bit_cast(unsigned short, h);
}
__device__ __forceinline__ float bs2f(unsigned short u) {
    return __uint_as_float(((unsigned int)u) << 16);
}
__device__ __forceinline__ float fast_cos(float x) {
    float rev = x * 0.15915494309189535f;   // 1/(2pi)
    rev = rev - rintf(rev);                 // revolutions, range-reduced
    return __builtin_amdgcn_cosf(rev);
}

// ---------------------------------------------------------------------------
// Kernel 0: weight transposes to bf16 (tiny).
// ---------------------------------------------------------------------------
__global__ __launch_bounds__(256) void convert_kernel(
    const float* __restrict__ We,
    const float* __restrict__ Wq, const float* __restrict__ Wk,
    const float* __restrict__ Wv, const float* __restrict__ Ws,
    unsigned short* __restrict__ WeT,
    unsigned short* __restrict__ WqT, unsigned short* __restrict__ WkT,
    unsigned short* __restrict__ WvT, unsigned short* __restrict__ WsT)
{
    const int T0  = ED * DO;            // 32768 (WeT)
    const int TOT = T0 + 4 * DIN * DO;  // + 4 node mats
    int i = blockIdx.x * 256 + threadIdx.x;
    if (i >= TOT) return;
    if (i < T0) {
        int n = i >> 8, k = i & 255;
        WeT[i] = f2bs(We[(size_t)k * DO + n]);
    } else {
        int j = i - T0; int m = j >> 14; int r = j & 16383;
        int n = r >> 7, k = r & 127;
        const float* W = (m == 0) ? Wq : (m == 1) ? Wk : (m == 2) ? Wv : Ws;
        unsigned short* WD = (m == 0) ? WqT : (m == 1) ? WkT : (m == 2) ? WvT : WsT;
        WD[r] = f2bs(W[(size_t)k * DO + n]);
    }
}

// ---------------------------------------------------------------------------
// Kernel 1: node projections via MFMA. 64 nodes/block, 256 threads (4 waves).
// ---------------------------------------------------------------------------
__global__ __launch_bounds__(256) void node_proj_kernel(
    const float* __restrict__ x,
    const unsigned short* __restrict__ WqT, const float* __restrict__ bq,
    const unsigned short* __restrict__ WkT, const float* __restrict__ bk,
    const unsigned short* __restrict__ WvT, const float* __restrict__ bv,
    const unsigned short* __restrict__ WsT, const float* __restrict__ bs,
    unsigned short* __restrict__ Qb, unsigned short* __restrict__ Kb,
    unsigned short* __restrict__ Vb, float* __restrict__ SKIP)
{
    __shared__ unsigned short xt[64 * 136];   // 64 nodes x 128k, pad +8
    const int tid = threadIdx.x;
    const int n0  = blockIdx.x * 64;

    #pragma unroll
    for (int i = 0; i < 8; ++i) {             // 64 rows x 32 float4 / 256 thr
        int q = i * 256 + tid; int row = q >> 5, c4 = q & 31;
        int gn = n0 + row; if (gn > NN - 1) gn = NN - 1;
        float4 v = ((const float4*)(x + (size_t)gn * DIN))[c4];
        u16x4 b; b.x = f2bs(v.x); b.y = f2bs(v.y); b.z = f2bs(v.z); b.w = f2bs(v.w);
        *(u16x4*)(xt + row * 136 + c4 * 4) = b;
    }
    __syncthreads();

    const int lane = tid & 63, w = tid >> 6;
    const int l15 = lane & 15, quad = lane >> 4;
    const unsigned short* arow = xt + (w * 16 + l15) * 136 + quad * 8;

    const unsigned short* WT[4] = {WqT, WkT, WvT, WsT};
    const float*          BI[4] = {bq, bk, bv, bs};

    #pragma unroll
    for (int m = 0; m < 4; ++m) {
        f32x4 acc[8];
        #pragma unroll
        for (int j = 0; j < 8; ++j) { float b = BI[m][j * 16 + l15]; acc[j] = {b, b, b, b}; }
        const unsigned short* Wm = WT[m];
        #pragma unroll
        for (int ks = 0; ks < 4; ++ks) {
            s16x8 a = *(const s16x8*)(arow + ks * 32);
            #pragma unroll
            for (int j = 0; j < 8; ++j) {
                s16x8 bf = *(const s16x8*)(Wm + (j * 16 + l15) * DIN + ks * 32 + quad * 8);
                acc[j] = __builtin_amdgcn_mfma_f32_16x16x32_bf16(a, bf, acc[j], 0, 0, 0);
            }
        }
        #pragma unroll
        for (int j = 0; j < 8; ++j) {
            int col = j * 16 + l15;
            #pragma unroll
            for (int r = 0; r < 4; ++r) {
                int node = n0 + w * 16 + quad * 4 + r;
                if (node < NN) {
                    float v = acc[j][r];
                    if (m == 0)      Qb[(size_t)node * DO + col] = f2bs(v);
                    else if (m == 1) Kb[(size_t)node * DO + col] = f2bs(v);
                    else if (m == 2) Vb[(size_t)node * DO + col] = f2bs(v);
                    else             SKIP[(size_t)node * DO + col] = v;
                }
            }
        }
    }
}

// ---------------------------------------------------------------------------
// Counting sort of edges by dst -> rowptr + rank (inverse permutation).
// ---------------------------------------------------------------------------
__global__ __launch_bounds__(256) void hist_kernel(
    const int* __restrict__ dstI, int* __restrict__ counts)
{
    int e = blockIdx.x * 256 + threadIdx.x;
    if (e < NE) atomicAdd(&counts[dstI[e]], 1);
}

__global__ __launch_bounds__(256) void scan1_kernel(
    const int* __restrict__ counts, int* __restrict__ bsum)
{
    __shared__ int s[256];
    int t = threadIdx.x; int i = blockIdx.x * 256 + t;
    s[t] = (i < NN) ? counts[i] : 0;
    __syncthreads();
    #pragma unroll
    for (int off = 128; off; off >>= 1) {
        if (t < off) s[t] += s[t + off];
        __syncthreads();
    }
    if (t == 0) bsum[blockIdx.x] = s[0];
}

__global__ __launch_bounds__(512) void scan2_kernel(int* __restrict__ bsum)
{
    __shared__ int s[512];
    int t = threadIdx.x;
    int v = (t < NBLK) ? bsum[t] : 0;
    s[t] = v; __syncthreads();
    for (int off = 1; off < 512; off <<= 1) {
        int add = (t >= off) ? s[t - off] : 0;
        __syncthreads();
        s[t] += add;
        __syncthreads();
    }
    if (t < NBLK) bsum[t] = s[t] - v;   // exclusive
}

__global__ __launch_bounds__(256) void scan3_kernel(
    const int* __restrict__ counts, const int* __restrict__ bsum,
    int* __restrict__ rowptr)
{
    __shared__ int s[256];
    int t = threadIdx.x; int i = blockIdx.x * 256 + t;
    int v = (i < NN) ? counts[i] : 0;
    s[t] = v; __syncthreads();
    for (int off = 1; off < 256; off <<= 1) {
        int add = (t >= off) ? s[t - off] : 0;
        __syncthreads();
        s[t] += add;
        __syncthreads();
    }
    if (i < NN) rowptr[i] = bsum[blockIdx.x] + s[t] - v;
    if (i == 0) rowptr[NN] = NE;
}

__global__ __launch_bounds__(256) void scatter_kernel(
    const int* __restrict__ dstI, const int* __restrict__ rowptr,
    int* __restrict__ cursor, int* __restrict__ rank)
{
    int e = blockIdx.x * 256 + threadIdx.x;
    if (e < NE) {
        int d = dstI[e];
        int pos = rowptr[d] + atomicAdd(&cursor[d], 1);
        rank[e] = pos;            // coalesced write; edge kernel scatters by rank
    }
}

// ---------------------------------------------------------------------------
// Kernel 2 (phase A): edge kernel. 32 edges/block, 256 threads (4 waves).
// LDS ~17.4KB -> up to 8 blocks/CU. Q/K/V gathers issued EARLY (hide under
// cos staging + MFMA). Tail: one 4-lane quad per edge-head, vector loads,
// 2-shuffle reduce, ONE pass (64 concurrent tasks/block).
// VE/EA written in dst-SORTED position via rank[] -> agg streams contiguously.
// ---------------------------------------------------------------------------
__global__ __launch_bounds__(256) void edge_kernel(
    const float* __restrict__ last_update, const float* __restrict__ tarr,
    const float* __restrict__ msg,
    const float* __restrict__ w_time, const float* __restrict__ b_time,
    const unsigned short* __restrict__ WeT,
    const int* __restrict__ srcI, const int* __restrict__ dstI,
    const int* __restrict__ rank,
    const unsigned short* __restrict__ Qb, const unsigned short* __restrict__ Kb,
    const unsigned short* __restrict__ Vb,
    unsigned short* __restrict__ VE, float* __restrict__ EA)
{
    // 32 rows x 528B: bf16 attr rows (264 elems = 256 + 8 pad),
    // then reused as fp32 e rows (132 elems = 128 + 4 pad).
    __shared__ char  smem[32 * 528];
    __shared__ int   ssrc[32], sdst[32], srk[32];
    __shared__ float srel[32];
    const int tid = threadIdx.x;
    const int e0  = blockIdx.x * 32;

    if (tid < 32) {
        int s = srcI[e0 + tid], d = dstI[e0 + tid];
        ssrc[tid] = s; sdst[tid] = d; srk[tid] = rank[e0 + tid];
        srel[tid] = last_update[s] - tarr[e0 + tid];
    }
    __syncthreads();

    // ---- early-issue Q/K/V gathers (consumed in the tail) ----
    const int ql   = tid & 3;            // lane in quad
    const int task = tid >> 2;           // 0..63
    const int te   = task >> 1;          // edge in block
    const int th   = task & 1;           // head
    const int tc0  = th * 64 + ql * 16;  // first col of this lane's 16-col slice
    const int ts = ssrc[te], td = sdst[te];
    const unsigned short* qp = Qb + (size_t)td * DO + tc0;
    const unsigned short* kp = Kb + (size_t)ts * DO + tc0;
    const unsigned short* vp = Vb + (size_t)ts * DO + tc0;
    u16x8 q0 = *(const u16x8*)qp,  q1 = *(const u16x8*)(qp + 8);
    u16x8 k0 = *(const u16x8*)kp,  k1 = *(const u16x8*)(kp + 8);
    u16x8 v0 = *(const u16x8*)vp,  v1 = *(const u16x8*)(vp + 8);

    // ---- stage attr (bf16) into LDS ----
    unsigned short* at = (unsigned short*)smem;
    const float4* msg4 = (const float4*)msg;
    #pragma unroll
    for (int i = 0; i < 4; ++i) {        // 32 rows x 32 float4 / 256 thr
        int q = i * 256 + tid; int e = q >> 5, c4 = q & 31;
        float4 m4 = msg4[(size_t)(e0 + e) * 32 + c4];
        u16x4 b; b.x = f2bs(m4.x); b.y = f2bs(m4.y); b.z = f2bs(m4.z); b.w = f2bs(m4.w);
        *(u16x4*)(at + e * 264 + c4 * 4) = b;
    }
    #pragma unroll
    for (int i = 0; i < 16; ++i) {       // 32 rows x 128 / 256 thr
        int q = i * 256 + tid; int e = q >> 7, j = q & 127;
        float v = fast_cos(srel[e] * w_time[j] + b_time[j]);
        at[e * 264 + MSGD + j] = f2bs(v);
    }
    __syncthreads();

    // ---- MFMA: wave w -> edges (w&1)*16.. x cols (w>>1)*64.. ----
    const int lane = tid & 63, w = tid >> 6;
    const int l15 = lane & 15, quad = lane >> 4;
    const int rh = (w & 1) * 16;
    const int chh = (w >> 1) * 64;

    f32x4 acc[4];
    #pragma unroll
    for (int j = 0; j < 4; ++j) acc[j] = {0.f, 0.f, 0.f, 0.f};
    const unsigned short* arow = at + (rh + l15) * 264 + quad * 8;
    #pragma unroll
    for (int ks = 0; ks < 8; ++ks) {
        s16x8 a = *(const s16x8*)(arow + ks * 32);
        #pragma unroll
        for (int j = 0; j < 4; ++j) {
            s16x8 b = *(const s16x8*)(WeT + (size_t)(chh + j * 16 + l15) * ED + ks * 32 + quad * 8);
            acc[j] = __builtin_amdgcn_mfma_f32_16x16x32_bf16(a, b, acc[j], 0, 0, 0);
        }
    }
    __syncthreads();   // attr fully consumed; reuse buffer for e (fp32)

    float* eld = (float*)smem;
    #pragma unroll
    for (int j = 0; j < 4; ++j) {
        #pragma unroll
        for (int r = 0; r < 4; ++r)
            eld[(rh + quad * 4 + r) * 132 + chh + j * 16 + l15] = acc[j][r];
    }
    __syncthreads();

    // ---- tail: one quad per edge-head, single pass ----
    const f32x4* ep4 = (const f32x4*)(eld + te * 132 + tc0);   // 528B rows: 16B-aligned
    float p = 0.f;
    u16x8 o0, o1;
    #pragma unroll
    for (int i = 0; i < 8; ++i) {
        float ev = ep4[i >> 2][i & 3];
        p += bs2f((unsigned short)q0[i]) * (bs2f((unsigned short)k0[i]) + ev);
        o0[i] = (unsigned short)f2bs(bs2f((unsigned short)v0[i]) + ev);
    }
    #pragma unroll
    for (int i = 0; i < 8; ++i) {
        float ev = ep4[2 + (i >> 2)][i & 3];
        p += bs2f((unsigned short)q1[i]) * (bs2f((unsigned short)k1[i]) + ev);
        o1[i] = (unsigned short)f2bs(bs2f((unsigned short)v1[i]) + ev);
    }
    p += __shfl_xor(p, 1, 64);
    p += __shfl_xor(p, 2, 64);
    float ea = __expf(p * 0.125f);                 // / sqrt(C=64)
    int pos = srk[te];
    unsigned short* vep = VE + (size_t)pos * DO + tc0;
    *(u16x8*)vep       = o0;
    *(u16x8*)(vep + 8) = o1;
    if (ql == 0) EA[(size_t)pos * 2 + th] = ea;
}

// ---------------------------------------------------------------------------
// Kernel 3 (phase B): node-major aggregation, one wave per node, no atomics.
// VE/EA are already dst-sorted -> pure streaming reads. 2-way unrolled.
// out[n][c] = (sum ea*VE) / (sum ea + 1e-16) + SKIP[n][c]
// Lane l handles cols 2l, 2l+1 (head = l>>5).
// ---------------------------------------------------------------------------
__global__ __launch_bounds__(256) void agg_kernel(
    const int* __restrict__ rowptr,
    const float* __restrict__ EA, const unsigned short* __restrict__ VE,
    const float* __restrict__ SKIP, float* __restrict__ out)
{
    int wid  = (blockIdx.x * 256 + threadIdx.x) >> 6;   // node
    int lane = threadIdx.x & 63;
    if (wid >= NN) return;
    int beg = rowptr[wid], end = rowptr[wid + 1];
    float a0 = 0.f, a1 = 0.f, den = 0.f;
    int j = beg;
    for (; j + 1 < end; j += 2) {
        float2 eaA = ((const float2*)EA)[j];
        float2 eaB = ((const float2*)EA)[j + 1];
        unsigned int pvA = ((const unsigned int*)(VE + (size_t)j * DO))[lane];
        unsigned int pvB = ((const unsigned int*)(VE + (size_t)(j + 1) * DO))[lane];
        float eA = (lane < 32) ? eaA.x : eaA.y;
        float eB = (lane < 32) ? eaB.x : eaB.y;
        den += eA + eB;
        a0 += eA * bs2f((unsigned short)(pvA & 0xffffu))
            + eB * bs2f((unsigned short)(pvB & 0xffffu));
        a1 += eA * bs2f((unsigned short)(pvA >> 16))
            + eB * bs2f((unsigned short)(pvB >> 16));
    }
    if (j < end) {
        float2 ea = ((const float2*)EA)[j];
        unsigned int pv = ((const unsigned int*)(VE + (size_t)j * DO))[lane];
        float eh = (lane < 32) ? ea.x : ea.y;
        den += eh;
        a0 += eh * bs2f((unsigned short)(pv & 0xffffu));
        a1 += eh * bs2f((unsigned short)(pv >> 16));
    }
    float inv = 1.0f / (den + 1e-16f);
    float2 sk = ((const float2*)SKIP)[(size_t)wid * 64 + lane];
    float2 o;
    o.x = a0 * inv + sk.x;
    o.y = a1 * inv + sk.y;
    ((float2*)out)[(size_t)wid * 64 + lane] = o;
}

extern "C" void kernel_launch(void* const* d_in, const int* in_sizes, int n_in,
                              void* d_out, int out_size, void* d_ws, size_t ws_size,
                              hipStream_t stream) {
    const float* x           = (const float*)d_in[0];
    const float* last_update = (const float*)d_in[1];
    const float* tarr        = (const float*)d_in[2];
    const float* msg         = (const float*)d_in[3];
    const float* w_time      = (const float*)d_in[4];
    const float* b_time      = (const float*)d_in[5];
    const float* Wq          = (const float*)d_in[6];
    const float* bq          = (const float*)d_in[7];
    const float* Wk          = (const float*)d_in[8];
    const float* bk          = (const float*)d_in[9];
    const float* Wv          = (const float*)d_in[10];
    const float* bv          = (const float*)d_in[11];
    const float* We          = (const float*)d_in[12];
    const float* Ws          = (const float*)d_in[13];
    const float* bs          = (const float*)d_in[14];
    const int*   ei          = (const int*)d_in[15];
    const int*   srcI = ei;
    const int*   dstI = ei + NE;

    float* out = (float*)d_out;
    char*  ws  = (char*)d_ws;
    // byte layout (all 16B-aligned)
    unsigned short* Qb   = (unsigned short*)(ws);                    // 25,600,000
    unsigned short* Kb   = (unsigned short*)(ws + 25600000);         // 25,600,000
    unsigned short* Vb   = (unsigned short*)(ws + 51200000);         // 25,600,000
    unsigned short* WeT  = (unsigned short*)(ws + 76800000);         // 65,536
    unsigned short* WqT  = (unsigned short*)(ws + 76865536);         // 32,768
    unsigned short* WkT  = (unsigned short*)(ws + 76898304);         // 32,768
    unsigned short* WvT  = (unsigned short*)(ws + 76931072);         // 32,768
    unsigned short* WsT  = (unsigned short*)(ws + 76963840);         // 32,768
    float*          SKIP = (float*)(ws + 76996608);                  // 51,200,000
    unsigned short* VE   = (unsigned short*)(ws + 128196608);        // 163,840,000
    float*          EA   = (float*)(ws + 292036608);                 // 5,120,000
    int*            rank = (int*)(ws + 297156608);                   // 2,560,000
    int*            counts = (int*)(ws + 299716608);                 // 400,000
    int*            cursor = (int*)(ws + 300116608);                 // 400,000
    int*            rowptr = (int*)(ws + 300516608);                 // 400,016
    int*            bsum   = (int*)(ws + 300916624);                 // 2,048

    // zero counts + cursor (contiguous, 800 KB)
    hipMemsetAsync(counts, 0, 800000, stream);

    convert_kernel<<<384, 256, 0, stream>>>(
        We, Wq, Wk, Wv, Ws, WeT, WqT, WkT, WvT, WsT);

    node_proj_kernel<<<(NN + 63) / 64, 256, 0, stream>>>(
        x, WqT, bq, WkT, bk, WvT, bv, WsT, bs, Qb, Kb, Vb, SKIP);

    // CSR build (counting sort by dst, inverse permutation)
    hist_kernel<<<(NE + 255) / 256, 256, 0, stream>>>(dstI, counts);
    scan1_kernel<<<NBLK, 256, 0, stream>>>(counts, bsum);
    scan2_kernel<<<1, 512, 0, stream>>>(bsum);
    scan3_kernel<<<NBLK, 256, 0, stream>>>(counts, bsum, rowptr);
    scatter_kernel<<<(NE + 255) / 256, 256, 0, stream>>>(dstI, rowptr, cursor, rank);

    edge_kernel<<<NE / 32, 256, 0, stream>>>(
        last_update, tarr, msg, w_time, b_time, WeT, srcI, dstI, rank,
        Qb, Kb, Vb, VE, EA);

    agg_kernel<<<(NN * 64 + 255) / 256, 256, 0, stream>>>(
        rowptr, EA, VE, SKIP, out);
}

// Round 4
// 941.157 us; speedup vs baseline: 1.2962x; 1.0679x over previous
//
#include <hip/hip_runtime.h>
#include <hip/hip_bf16.h>
#include <math.h>

// Problem constants (fixed by reference file)
#define NN   100000   // nodes
#define NE   640000   // edges
#define DIN  128      // in_channels
#define DO   128      // out_channels (H*C)
#define ED   256      // edge dim (MSG + TD)
#define MSGD 128
#define NBLK 391      // ceil(NN/256) for scan kernels

typedef __attribute__((ext_vector_type(8))) short s16x8;           // 8 bf16 (A/B frag)
typedef __attribute__((ext_vector_type(4))) float f32x4;           // C/D frag
typedef __attribute__((ext_vector_type(4))) unsigned short u16x4;
typedef __attribute__((ext_vector_type(8))) unsigned short u16x8;

__device__ __forceinline__ unsigned short f2bs(float f) {
    __hip_bfloat16 h = __float2bfloat16(f);   // RNE
    return __builtin_bit_cast(unsigned short, h);
}
__device__ __forceinline__ float bs2f(unsigned short u) {
    return __uint_as_float(((unsigned int)u) << 16);
}
__device__ __forceinline__ float fast_cos(float x) {
    float rev = x * 0.15915494309189535f;   // 1/(2pi)
    rev = rev - rintf(rev);                 // revolutions, range-reduced
    return __builtin_amdgcn_cosf(rev);
}

// ---------------------------------------------------------------------------
// Kernel 0: weight transposes to bf16 + dst histogram (merged; tiny).
// ---------------------------------------------------------------------------
__global__ __launch_bounds__(256) void convert_hist_kernel(
    const float* __restrict__ We,
    const float* __restrict__ Wq, const float* __restrict__ Wk,
    const float* __restrict__ Wv, const float* __restrict__ Ws,
    unsigned short* __restrict__ WeT,
    unsigned short* __restrict__ WqT, unsigned short* __restrict__ WkT,
    unsigned short* __restrict__ WvT, unsigned short* __restrict__ WsT,
    const int* __restrict__ dstI, int* __restrict__ counts)
{
    const int T0  = ED * DO;            // 32768 (WeT)
    const int TOT = T0 + 4 * DIN * DO;  // + 4 node mats
    int i = blockIdx.x * 256 + threadIdx.x;
    if (i < TOT) {
        if (i < T0) {
            int n = i >> 8, k = i & 255;
            WeT[i] = f2bs(We[(size_t)k * DO + n]);
        } else {
            int j = i - T0; int m = j >> 14; int r = j & 16383;
            int n = r >> 7, k = r & 127;
            const float* W = (m == 0) ? Wq : (m == 1) ? Wk : (m == 2) ? Wv : Ws;
            unsigned short* WD = (m == 0) ? WqT : (m == 1) ? WkT : (m == 2) ? WvT : WsT;
            WD[r] = f2bs(W[(size_t)k * DO + n]);
        }
    }
    if (i < NE) atomicAdd(&counts[dstI[i]], 1);
}

// ---------------------------------------------------------------------------
// Kernel 1: node projections via MFMA. 64 nodes/block, 256 threads (4 waves).
// Swapped operands: A = W (row = out-col), B = x (col = node) -> per-lane 4
// contiguous out-cols => vectorized u16x4 / f32x4 stores, f32x4 bias init.
// SKIP is written DIRECTLY into d_out (agg adds in place) - no SKIP buffer.
// ---------------------------------------------------------------------------
__global__ __launch_bounds__(256) void node_proj_kernel(
    const float* __restrict__ x,
    const unsigned short* __restrict__ WqT, const float* __restrict__ bq,
    const unsigned short* __restrict__ WkT, const float* __restrict__ bk,
    const unsigned short* __restrict__ WvT, const float* __restrict__ bv,
    const unsigned short* __restrict__ WsT, const float* __restrict__ bs,
    unsigned short* __restrict__ Qb, unsigned short* __restrict__ Kb,
    unsigned short* __restrict__ Vb, float* __restrict__ out)
{
    __shared__ unsigned short xt[64 * 136];   // 64 nodes x 128k, pad +8
    const int tid = threadIdx.x;
    const int n0  = blockIdx.x * 64;

    #pragma unroll
    for (int i = 0; i < 8; ++i) {             // 64 rows x 32 float4 / 256 thr
        int q = i * 256 + tid; int row = q >> 5, c4 = q & 31;
        int gn = n0 + row; if (gn > NN - 1) gn = NN - 1;
        float4 v = ((const float4*)(x + (size_t)gn * DIN))[c4];
        u16x4 b; b.x = f2bs(v.x); b.y = f2bs(v.y); b.z = f2bs(v.z); b.w = f2bs(v.w);
        *(u16x4*)(xt + row * 136 + c4 * 4) = b;
    }
    __syncthreads();

    const int lane = tid & 63, w = tid >> 6;
    const int l15 = lane & 15, quad = lane >> 4;
    const unsigned short* brow = xt + (w * 16 + l15) * 136 + quad * 8;  // B = x, col=node
    const int node = n0 + w * 16 + l15;

    const unsigned short* WT[4] = {WqT, WkT, WvT, WsT};
    const float*          BI[4] = {bq, bk, bv, bs};

    #pragma unroll
    for (int m = 0; m < 4; ++m) {
        f32x4 acc[8];
        #pragma unroll
        for (int j = 0; j < 8; ++j)
            acc[j] = *(const f32x4*)(BI[m] + j * 16 + quad * 4);
        const unsigned short* Wm = WT[m];
        #pragma unroll
        for (int ks = 0; ks < 4; ++ks) {
            s16x8 bx = *(const s16x8*)(brow + ks * 32);
            #pragma unroll
            for (int j = 0; j < 8; ++j) {
                s16x8 aw = *(const s16x8*)(Wm + (size_t)(j * 16 + l15) * DIN + ks * 32 + quad * 8);
                acc[j] = __builtin_amdgcn_mfma_f32_16x16x32_bf16(aw, bx, acc[j], 0, 0, 0);
            }
        }
        if (node < NN) {
            #pragma unroll
            for (int j = 0; j < 8; ++j) {
                int c0 = j * 16 + quad * 4;
                if (m == 3) {
                    *(f32x4*)(out + (size_t)node * DO + c0) = acc[j];
                } else {
                    u16x4 pk;
                    pk.x = f2bs(acc[j][0]); pk.y = f2bs(acc[j][1]);
                    pk.z = f2bs(acc[j][2]); pk.w = f2bs(acc[j][3]);
                    unsigned short* Dst = (m == 0) ? Qb : (m == 1) ? Kb : Vb;
                    *(u16x4*)(Dst + (size_t)node * DO + c0) = pk;
                }
            }
        }
    }
}

// ---------------------------------------------------------------------------
// Scan chain for counting sort by dst.
// ---------------------------------------------------------------------------
__global__ __launch_bounds__(256) void scan1_kernel(
    const int* __restrict__ counts, int* __restrict__ bsum)
{
    __shared__ int s[256];
    int t = threadIdx.x; int i = blockIdx.x * 256 + t;
    s[t] = (i < NN) ? counts[i] : 0;
    __syncthreads();
    #pragma unroll
    for (int off = 128; off; off >>= 1) {
        if (t < off) s[t] += s[t + off];
        __syncthreads();
    }
    if (t == 0) bsum[blockIdx.x] = s[0];
}

__global__ __launch_bounds__(512) void scan2_kernel(int* __restrict__ bsum)
{
    __shared__ int s[512];
    int t = threadIdx.x;
    int v = (t < NBLK) ? bsum[t] : 0;
    s[t] = v; __syncthreads();
    for (int off = 1; off < 512; off <<= 1) {
        int add = (t >= off) ? s[t - off] : 0;
        __syncthreads();
        s[t] += add;
        __syncthreads();
    }
    if (t < NBLK) bsum[t] = s[t] - v;   // exclusive
}

__global__ __launch_bounds__(256) void scan3_kernel(
    const int* __restrict__ counts, const int* __restrict__ bsum,
    int* __restrict__ rowptr)
{
    __shared__ int s[256];
    int t = threadIdx.x; int i = blockIdx.x * 256 + t;
    int v = (i < NN) ? counts[i] : 0;
    s[t] = v; __syncthreads();
    for (int off = 1; off < 256; off <<= 1) {
        int add = (t >= off) ? s[t - off] : 0;
        __syncthreads();
        s[t] += add;
        __syncthreads();
    }
    if (i < NN) rowptr[i] = bsum[blockIdx.x] + s[t] - v;
    if (i == 0) rowptr[NN] = NE;
}

// scatter: emit sorted-position metadata as ONE int4 {src, dst, perm, relbits}
__global__ __launch_bounds__(256) void scatter_kernel(
    const int* __restrict__ srcI, const int* __restrict__ dstI,
    const float* __restrict__ last_update, const float* __restrict__ tarr,
    const int* __restrict__ rowptr, int* __restrict__ cursor,
    int4* __restrict__ meta)
{
    int e = blockIdx.x * 256 + threadIdx.x;
    if (e < NE) {
        int d = dstI[e], s = srcI[e];
        int pos = rowptr[d] + atomicAdd(&cursor[d], 1);
        float rel = last_update[s] - tarr[e];
        meta[pos] = make_int4(s, d, e, __float_as_int(rel));
    }
}

// ---------------------------------------------------------------------------
// Kernel 2 (phase A): edge kernel over DST-SORTED edges. 64 edges/block,
// 256 threads (4 waves). Sorted order => Q-row gathers hit L1 (shared dst),
// VE/EA stores are sequential. Swapped MFMA operands => W-frag reused for 2
// edge-groups (halves WeT L2 traffic) and b128 eld writeback.
// Tail: 2 tasks/thread (quad per edge-head), 12 gathers in flight.
// ---------------------------------------------------------------------------
__global__ __launch_bounds__(256) void edge_kernel(
    const float* __restrict__ msg,
    const float* __restrict__ w_time, const float* __restrict__ b_time,
    const unsigned short* __restrict__ WeT,
    const int4* __restrict__ meta,
    const unsigned short* __restrict__ Qb, const unsigned short* __restrict__ Kb,
    const unsigned short* __restrict__ Vb,
    unsigned short* __restrict__ VE, float* __restrict__ EA)
{
    // 64 rows x 528B: bf16 attr rows (264 elems = 256 + 8 pad),
    // then reused as fp32 e rows (132 elems = 128 + 4 pad).
    __shared__ char  smem[64 * 528];
    __shared__ int   ssrc[64], sdst[64], sperm[64];
    __shared__ float srel[64];
    const int tid = threadIdx.x;
    const int e0  = blockIdx.x * 64;

    if (tid < 64) {
        int4 m = meta[e0 + tid];
        ssrc[tid]  = m.x;
        sdst[tid]  = m.y;
        sperm[tid] = m.z;
        srel[tid]  = __int_as_float(m.w);
    }
    __syncthreads();

    // ---- early-issue Q/K/V gathers for both tasks (consumed in tail) ----
    const int ql  = tid & 3;             // lane in quad
    const int th  = (tid >> 2) & 1;      // head
    const int te  = tid >> 3;            // edge A (0..31); edge B = te+32
    const int tc0 = th * 64 + ql * 16;   // first col of this lane's 16-col slice
    const int sA = ssrc[te],      dA = sdst[te];
    const int sB = ssrc[te + 32], dB = sdst[te + 32];
    const unsigned short* qpA = Qb + (size_t)dA * DO + tc0;
    const unsigned short* kpA = Kb + (size_t)sA * DO + tc0;
    const unsigned short* vpA = Vb + (size_t)sA * DO + tc0;
    const unsigned short* qpB = Qb + (size_t)dB * DO + tc0;
    const unsigned short* kpB = Kb + (size_t)sB * DO + tc0;
    const unsigned short* vpB = Vb + (size_t)sB * DO + tc0;
    u16x8 qA0 = *(const u16x8*)qpA, qA1 = *(const u16x8*)(qpA + 8);
    u16x8 kA0 = *(const u16x8*)kpA, kA1 = *(const u16x8*)(kpA + 8);
    u16x8 vA0 = *(const u16x8*)vpA, vA1 = *(const u16x8*)(vpA + 8);
    u16x8 qB0 = *(const u16x8*)qpB, qB1 = *(const u16x8*)(qpB + 8);
    u16x8 kB0 = *(const u16x8*)kpB, kB1 = *(const u16x8*)(kpB + 8);
    u16x8 vB0 = *(const u16x8*)vpB, vB1 = *(const u16x8*)(vpB + 8);

    // ---- stage attr (bf16) into LDS: msg rows gathered by perm ----
    unsigned short* at = (unsigned short*)smem;
    const float4* msg4 = (const float4*)msg;
    #pragma unroll
    for (int i = 0; i < 8; ++i) {        // 64 rows x 32 float4 / 256 thr
        int q = i * 256 + tid; int e = q >> 5, c4 = q & 31;
        float4 m4 = msg4[(size_t)sperm[e] * 32 + c4];
        u16x4 b; b.x = f2bs(m4.x); b.y = f2bs(m4.y); b.z = f2bs(m4.z); b.w = f2bs(m4.w);
        *(u16x4*)(at + e * 264 + c4 * 4) = b;
    }
    #pragma unroll
    for (int i = 0; i < 32; ++i) {       // 64 rows x 128 / 256 thr
        int q = i * 256 + tid; int e = q >> 7, j = q & 127;
        float v = fast_cos(srel[e] * w_time[j] + b_time[j]);
        at[e * 264 + MSGD + j] = f2bs(v);
    }
    __syncthreads();

    // ---- MFMA (swapped): wave w -> col-half (w&1), edge-groups 2*(w>>1), +1
    const int lane = tid & 63, w = tid >> 6;
    const int l15 = lane & 15, quad = lane >> 4;
    const int chh = (w & 1) * 64;
    const int g0  = (w >> 1) * 2, g1 = g0 + 1;

    f32x4 acc0[4], acc1[4];
    #pragma unroll
    for (int j = 0; j < 4; ++j) { acc0[j] = {0.f,0.f,0.f,0.f}; acc1[j] = {0.f,0.f,0.f,0.f}; }
    const unsigned short* b0row = at + (g0 * 16 + l15) * 264 + quad * 8;
    const unsigned short* b1row = at + (g1 * 16 + l15) * 264 + quad * 8;
    #pragma unroll
    for (int ks = 0; ks < 8; ++ks) {
        s16x8 b0 = *(const s16x8*)(b0row + ks * 32);
        s16x8 b1 = *(const s16x8*)(b1row + ks * 32);
        #pragma unroll
        for (int j = 0; j < 4; ++j) {
            s16x8 a = *(const s16x8*)(WeT + (size_t)(chh + j * 16 + l15) * ED + ks * 32 + quad * 8);
            acc0[j] = __builtin_amdgcn_mfma_f32_16x16x32_bf16(a, b0, acc0[j], 0, 0, 0);
            acc1[j] = __builtin_amdgcn_mfma_f32_16x16x32_bf16(a, b1, acc1[j], 0, 0, 0);
        }
    }
    __syncthreads();   // attr fully consumed; reuse buffer for e (fp32)

    float* eld = (float*)smem;
    #pragma unroll
    for (int j = 0; j < 4; ++j) {
        *(f32x4*)(eld + (g0 * 16 + l15) * 132 + chh + j * 16 + quad * 4) = acc0[j];
        *(f32x4*)(eld + (g1 * 16 + l15) * 132 + chh + j * 16 + quad * 4) = acc1[j];
    }
    __syncthreads();

    // ---- tail: 2 tasks/thread, one quad per edge-head, single pass ----
    {   // task A (edge te)
        const f32x4* ep4 = (const f32x4*)(eld + te * 132 + tc0);
        float p = 0.f;
        u16x8 o0, o1;
        #pragma unroll
        for (int i = 0; i < 8; ++i) {
            float ev = ep4[i >> 2][i & 3];
            p += bs2f((unsigned short)qA0[i]) * (bs2f((unsigned short)kA0[i]) + ev);
            o0[i] = (unsigned short)f2bs(bs2f((unsigned short)vA0[i]) + ev);
        }
        #pragma unroll
        for (int i = 0; i < 8; ++i) {
            float ev = ep4[2 + (i >> 2)][i & 3];
            p += bs2f((unsigned short)qA1[i]) * (bs2f((unsigned short)kA1[i]) + ev);
            o1[i] = (unsigned short)f2bs(bs2f((unsigned short)vA1[i]) + ev);
        }
        p += __shfl_xor(p, 1, 64);
        p += __shfl_xor(p, 2, 64);
        float ea = __expf(p * 0.125f);                 // / sqrt(C=64)
        unsigned short* vep = VE + (size_t)(e0 + te) * DO + tc0;
        *(u16x8*)vep       = o0;
        *(u16x8*)(vep + 8) = o1;
        if (ql == 0) EA[(size_t)(e0 + te) * 2 + th] = ea;
    }
    {   // task B (edge te+32)
        const f32x4* ep4 = (const f32x4*)(eld + (te + 32) * 132 + tc0);
        float p = 0.f;
        u16x8 o0, o1;
        #pragma unroll
        for (int i = 0; i < 8; ++i) {
            float ev = ep4[i >> 2][i & 3];
            p += bs2f((unsigned short)qB0[i]) * (bs2f((unsigned short)kB0[i]) + ev);
            o0[i] = (unsigned short)f2bs(bs2f((unsigned short)vB0[i]) + ev);
        }
        #pragma unroll
        for (int i = 0; i < 8; ++i) {
            float ev = ep4[2 + (i >> 2)][i & 3];
            p += bs2f((unsigned short)qB1[i]) * (bs2f((unsigned short)kB1[i]) + ev);
            o1[i] = (unsigned short)f2bs(bs2f((unsigned short)vB1[i]) + ev);
        }
        p += __shfl_xor(p, 1, 64);
        p += __shfl_xor(p, 2, 64);
        float ea = __expf(p * 0.125f);
        unsigned short* vep = VE + (size_t)(e0 + te + 32) * DO + tc0;
        *(u16x8*)vep       = o0;
        *(u16x8*)(vep + 8) = o1;
        if (ql == 0) EA[(size_t)(e0 + te + 32) * 2 + th] = ea;
    }
}

// ---------------------------------------------------------------------------
// Kernel 3 (phase B): node-major aggregation, one wave per node, no atomics.
// VE/EA are dst-sorted -> pure streaming reads. 2-way unrolled.
// out already holds SKIP: out = acc/den + out (in place).
// ---------------------------------------------------------------------------
__global__ __launch_bounds__(256) void agg_kernel(
    const int* __restrict__ rowptr,
    const float* __restrict__ EA, const unsigned short* __restrict__ VE,
    float* __restrict__ out)
{
    int wid  = (blockIdx.x * 256 + threadIdx.x) >> 6;   // node
    int lane = threadIdx.x & 63;
    if (wid >= NN) return;
    int beg = rowptr[wid], end = rowptr[wid + 1];
    float a0 = 0.f, a1 = 0.f, den = 0.f;
    int j = beg;
    for (; j + 1 < end; j += 2) {
        float2 eaA = ((const float2*)EA)[j];
        float2 eaB = ((const float2*)EA)[j + 1];
        unsigned int pvA = ((const unsigned int*)(VE + (size_t)j * DO))[lane];
        unsigned int pvB = ((const unsigned int*)(VE + (size_t)(j + 1) * DO))[lane];
        float eA = (lane < 32) ? eaA.x : eaA.y;
        float eB = (lane < 32) ? eaB.x : eaB.y;
        den += eA + eB;
        a0 += eA * bs2f((unsigned short)(pvA & 0xffffu))
            + eB * bs2f((unsigned short)(pvB & 0xffffu));
        a1 += eA * bs2f((unsigned short)(pvA >> 16))
            + eB * bs2f((unsigned short)(pvB >> 16));
    }
    if (j < end) {
        float2 ea = ((const float2*)EA)[j];
        unsigned int pv = ((const unsigned int*)(VE + (size_t)j * DO))[lane];
        float eh = (lane < 32) ? ea.x : ea.y;
        den += eh;
        a0 += eh * bs2f((unsigned short)(pv & 0xffffu));
        a1 += eh * bs2f((unsigned short)(pv >> 16));
    }
    float inv = 1.0f / (den + 1e-16f);
    float2 sk = ((const float2*)out)[(size_t)wid * 64 + lane];   // skip (pre-written)
    float2 o;
    o.x = a0 * inv + sk.x;
    o.y = a1 * inv + sk.y;
    ((float2*)out)[(size_t)wid * 64 + lane] = o;
}

extern "C" void kernel_launch(void* const* d_in, const int* in_sizes, int n_in,
                              void* d_out, int out_size, void* d_ws, size_t ws_size,
                              hipStream_t stream) {
    const float* x           = (const float*)d_in[0];
    const float* last_update = (const float*)d_in[1];
    const float* tarr        = (const float*)d_in[2];
    const float* msg         = (const float*)d_in[3];
    const float* w_time      = (const float*)d_in[4];
    const float* b_time      = (const float*)d_in[5];
    const float* Wq          = (const float*)d_in[6];
    const float* bq          = (const float*)d_in[7];
    const float* Wk          = (const float*)d_in[8];
    const float* bk          = (const float*)d_in[9];
    const float* Wv          = (const float*)d_in[10];
    const float* bv          = (const float*)d_in[11];
    const float* We          = (const float*)d_in[12];
    const float* Ws          = (const float*)d_in[13];
    const float* bs          = (const float*)d_in[14];
    const int*   ei          = (const int*)d_in[15];
    const int*   srcI = ei;
    const int*   dstI = ei + NE;

    float* out = (float*)d_out;
    char*  ws  = (char*)d_ws;
    // byte layout (all 16B-aligned), total ~257.4 MB
    unsigned short* Qb   = (unsigned short*)(ws);                    // 25,600,000
    unsigned short* Kb   = (unsigned short*)(ws + 25600000);         // 25,600,000
    unsigned short* Vb   = (unsigned short*)(ws + 51200000);         // 25,600,000
    unsigned short* WeT  = (unsigned short*)(ws + 76800000);         // 65,536
    unsigned short* WqT  = (unsigned short*)(ws + 76865536);         // 32,768
    unsigned short* WkT  = (unsigned short*)(ws + 76898304);         // 32,768
    unsigned short* WvT  = (unsigned short*)(ws + 76931072);         // 32,768
    unsigned short* WsT  = (unsigned short*)(ws + 76963840);         // 32,768
    unsigned short* VE   = (unsigned short*)(ws + 76996608);         // 163,840,000
    float*          EA   = (float*)(ws + 240836608);                 // 5,120,000
    int4*           meta = (int4*)(ws + 245956608);                  // 10,240,000
    int*            rowptr = (int*)(ws + 256196608);                 // 400,016
    int*            counts = (int*)(ws + 256596624);                 // 400,000
    int*            cursor = (int*)(ws + 256996624);                 // 400,000
    int*            bsum   = (int*)(ws + 257396624);                 // 2,048

    // zero counts + cursor (contiguous, 800 KB)
    hipMemsetAsync(counts, 0, 800000, stream);

    convert_hist_kernel<<<(NE + 255) / 256, 256, 0, stream>>>(
        We, Wq, Wk, Wv, Ws, WeT, WqT, WkT, WvT, WsT, dstI, counts);

    node_proj_kernel<<<(NN + 63) / 64, 256, 0, stream>>>(
        x, WqT, bq, WkT, bk, WvT, bv, WsT, bs, Qb, Kb, Vb, out);

    // CSR build (counting sort by dst) + sorted metadata
    scan1_kernel<<<NBLK, 256, 0, stream>>>(counts, bsum);
    scan2_kernel<<<1, 512, 0, stream>>>(bsum);
    scan3_kernel<<<NBLK, 256, 0, stream>>>(counts, bsum, rowptr);
    scatter_kernel<<<(NE + 255) / 256, 256, 0, stream>>>(
        srcI, dstI, last_update, tarr, rowptr, cursor, meta);

    edge_kernel<<<NE / 64, 256, 0, stream>>>(
        msg, w_time, b_time, WeT, meta, Qb, Kb, Vb, VE, EA);

    agg_kernel<<<(NN * 64 + 255) / 256, 256, 0, stream>>>(
        rowptr, EA, VE, out);
}